// Round 2
// baseline (292.285 us; speedup 1.0000x reference)
//
#include <hip/hip_runtime.h>
#include <math.h>

#define EPSF    1e-8f
#define SLOPEF  0.2f
#define GS_EPSF 1e-6f

#define NB   4
#define KZ   4
#define BKT  16     // NB*KZ
#define NPT  2048
#define DIM  32

// ---------------------------------------------------------------------------
// Kernel 0: cA[bk*2048+n] = (ch0,ch1,ch2,ch3), cB = (ch4,ch5,xx,0)
// channel = c*3+j per reference flattening (x.reshape(b*k, 3*d? no: transpose
// gives x[bk][d=2? ]) -- channels 0..5 are (c,j) flattened as c*3+j.
// ---------------------------------------------------------------------------
__global__ __launch_bounds__(256) void prep_coords(
    const float* __restrict__ node, const float* __restrict__ z,
    float4* __restrict__ cA, float4* __restrict__ cB) {
  int t = blockIdx.x * 256 + threadIdx.x;
  if (t >= BKT * NPT) return;
  int bk = t >> 11, n = t & (NPT - 1);
  int b = bk >> 2, kz = bk & 3;
  const float2* np2 = (const float2*)(node + (size_t)(b * NPT + n) * 6);
  const float2* zp2 = (const float2*)(z + (size_t)((b * KZ + kz) * NPT + n) * 6);
  float ch[6];
#pragma unroll
  for (int j = 0; j < 3; ++j) {           // float2 = (c=0,j),(c=1,j) -> ch j, ch 3+j
    float2 a = np2[j], c = zp2[j];
    ch[j]     = a.x + c.x;
    ch[3 + j] = a.y + c.y;
  }
  float xx = 0.f;
#pragma unroll
  for (int h = 0; h < 6; ++h) xx = fmaf(ch[h], ch[h], xx);
  cA[t] = make_float4(ch[0], ch[1], ch[2], ch[3]);
  cB[t] = make_float4(ch[4], ch[5], xx, 0.f);
}

// ---------------------------------------------------------------------------
// Kernel 1: top-4 KNN. Wave = 16 queries (4 lanes each); lane scans 512 pts.
// Rank by s = dot(q,p) - 0.5*||p||^2  (== neg_dist/2 + const(q): order-equal).
// Ties -> lower index at every level (strict '>', ascending scan; ce idx-asc).
// ---------------------------------------------------------------------------
__device__ __forceinline__ void ce(float& vx, int& ix, float& vy, int& iy) {
  float av = vx, bv = vy; int ai = ix, bi = iy;
  bool sw = (bv > av) || (bv == av && bi < ai);
  vx = sw ? bv : av; vy = sw ? av : bv;
  ix = sw ? bi : ai; iy = sw ? ai : bi;
}

__global__ __launch_bounds__(256) void knn_kernel(
    const float4* __restrict__ cA, const float4* __restrict__ cB,
    int4* __restrict__ knn4) {
  int wv = threadIdx.x >> 6, lane = threadIdx.x & 63;
  int g = lane >> 2, sub = lane & 3;
  int bk = blockIdx.x >> 5, qc = blockIdx.x & 31;
  int q = qc * 64 + wv * 16 + g;
  int base = bk * NPT;
  float4 qa = cA[base + q];
  float4 qb = cB[base + q];
  const float4* pa = cA + base + sub * 512;
  const float4* pb = cB + base + sub * 512;
  float v0 = -INFINITY, v1 = -INFINITY, v2 = -INFINITY, v3 = -INFINITY;
  int   i0 = 0x7fffffff, i1 = 0x7fffffff, i2 = 0x7fffffff, i3 = 0x7fffffff;
#pragma unroll 4
  for (int t = 0; t < 512; ++t) {
    float4 A = pa[t], B = pb[t];
    float s = qa.x * A.x;
    s = fmaf(qa.y, A.y, s);
    s = fmaf(qa.z, A.z, s);
    s = fmaf(qa.w, A.w, s);
    s = fmaf(qb.x, B.x, s);
    s = fmaf(qb.y, B.y, s);
    s = fmaf(-0.5f, B.z, s);
    if (s > v3) {
      int j = sub * 512 + t;
      if (s > v2) {
        v3 = v2; i3 = i2;
        if (s > v1) {
          v2 = v1; i2 = i1;
          if (s > v0) { v1 = v0; i1 = i0; v0 = s; i0 = j; }
          else        { v1 = s; i1 = j; }
        } else { v2 = s; i2 = j; }
      } else { v3 = s; i3 = j; }
    }
  }
  // merge the 4 lanes of each query group: xor 1 then xor 2 (stay in group)
#pragma unroll
  for (int off = 1; off <= 2; off <<= 1) {
    float b0 = __shfl_xor(v0, off), b1 = __shfl_xor(v1, off);
    float b2 = __shfl_xor(v2, off), b3 = __shfl_xor(v3, off);
    int   j0 = __shfl_xor(i0, off), j1 = __shfl_xor(i1, off);
    int   j2 = __shfl_xor(i2, off), j3 = __shfl_xor(i3, off);
    float s4 = b3, s5 = b2, s6 = b1, s7 = b0;
    int   t4 = j3, t5 = j2, t6 = j1, t7 = j0;
    ce(v0, i0, s4, t4); ce(v1, i1, s5, t5);
    ce(v2, i2, s6, t6); ce(v3, i3, s7, t7);
    ce(v0, i0, v2, i2); ce(v1, i1, v3, i3);
    ce(v0, i0, v1, i1); ce(v2, i2, v3, i3);
  }
  if (sub == 0) knn4[base + q] = make_int4(i0, i1, i2, i3);
}

// ---------------------------------------------------------------------------
// Kernel 2: per point: G -> p,d -> leaky -> h; pool over k -> x1; dot3;
// in-block argmax over 4 points -> partials[bk][pb][o] = (x1, dot3)
// ---------------------------------------------------------------------------
__global__ __launch_bounds__(128) void feature_kernel(
    const float4* __restrict__ cA, const float4* __restrict__ cB,
    const int4* __restrict__ knn4,
    const float* __restrict__ W1f, const float* __restrict__ W1d,
    const float* __restrict__ Wp1, const float* __restrict__ Wp3,
    float4* __restrict__ partials) {
  __shared__ float4 hlds[4][4][DIM];     // [p][kk][c]
  __shared__ float4 x1lds[4][DIM];       // [p][c] : x1 vec
  __shared__ float  dlds[4][DIM];        // [p][o] : dot3
  __shared__ float  wp1T[DIM * DIM], wp3T[DIM * DIM];  // [c][o]
  for (int i = threadIdx.x; i < DIM * DIM; i += 128) {
    int o = i & 31, c = i >> 5;
    wp1T[i] = Wp1[o * 32 + c];
    wp3T[i] = Wp3[o * 32 + c];
  }
  int p = threadIdx.x >> 5, o = threadIdx.x & 31;
  int bk = blockIdx.x >> 9, pb = blockIdx.x & 511;
  int n = (pb << 2) | p;
  int base = bk * NPT;
  float4 ca = cA[base + n], cb = cB[base + n];
  float ct[6] = {ca.x, ca.y, ca.z, ca.w, cb.x, cb.y};
  float4 wf = reinterpret_cast<const float4*>(W1f)[o];
  float4 wd = reinterpret_cast<const float4*>(W1d)[o];
  float w1f[4] = {wf.x, wf.y, wf.z, wf.w};
  float w1d[4] = {wd.x, wd.y, wd.z, wd.w};
  int4 nb = knn4[base + n];
  int nbi[4] = {nb.x, nb.y, nb.z, nb.w};
  float h[4][3];
#pragma unroll
  for (int kk = 0; kk < 4; ++kk) {
    int m = nbi[kk];
    float4 A = cA[base + m], B = cB[base + m];
    float nc[6] = {A.x, A.y, A.z, A.w, B.x, B.y};
    float G[4][3];
#pragma unroll
    for (int j = 0; j < 3; ++j) {
      G[0][j] = nc[j] - ct[j];
      G[1][j] = nc[3 + j] - ct[3 + j];
      G[2][j] = ct[j];
      G[3][j] = ct[3 + j];
    }
    float pv[3], dv[3];
#pragma unroll
    for (int j = 0; j < 3; ++j) {
      float a = 0.f, dd = 0.f;
#pragma unroll
      for (int c = 0; c < 4; ++c) { a = fmaf(w1f[c], G[c][j], a); dd = fmaf(w1d[c], G[c][j], dd); }
      pv[j] = a; dv[j] = dd;
    }
    float dot = pv[0] * dv[0] + pv[1] * dv[1] + pv[2] * dv[2];
    float d2  = dv[0] * dv[0] + dv[1] * dv[1] + dv[2] * dv[2];
    float fac = dot / (d2 + EPSF);
#pragma unroll
    for (int j = 0; j < 3; ++j) {
      float negj = pv[j] - fac * dv[j];
      float sel = (dot >= 0.f) ? pv[j] : negj;
      h[kk][j] = SLOPEF * pv[j] + (1.f - SLOPEF) * sel;
    }
    hlds[p][kk][o] = make_float4(h[kk][0], h[kk][1], h[kk][2], 0.f);
  }
  __syncthreads();
  float d1[4][3] = {};
  for (int c = 0; c < 32; ++c) {
    float wp = wp1T[c * 32 + o];
#pragma unroll
    for (int kk = 0; kk < 4; ++kk) {
      float4 hv = hlds[p][kk][c];
      d1[kk][0] = fmaf(wp, hv.x, d1[kk][0]);
      d1[kk][1] = fmaf(wp, hv.y, d1[kk][1]);
      d1[kk][2] = fmaf(wp, hv.z, d1[kk][2]);
    }
  }
  float best = -INFINITY;
  float x1[3] = {0.f, 0.f, 0.f};
#pragma unroll
  for (int kk = 0; kk < 4; ++kk) {
    float dt = h[kk][0] * d1[kk][0] + h[kk][1] * d1[kk][1] + h[kk][2] * d1[kk][2];
    if (dt > best) { best = dt; x1[0] = h[kk][0]; x1[1] = h[kk][1]; x1[2] = h[kk][2]; }
  }
  x1lds[p][o] = make_float4(x1[0], x1[1], x1[2], 0.f);
  __syncthreads();
  float d3[3] = {0.f, 0.f, 0.f};
  for (int c = 0; c < 32; ++c) {
    float wp = wp3T[c * 32 + o];
    float4 xv = x1lds[p][c];
    d3[0] = fmaf(wp, xv.x, d3[0]);
    d3[1] = fmaf(wp, xv.y, d3[1]);
    d3[2] = fmaf(wp, xv.z, d3[2]);
  }
  dlds[p][o] = x1[0] * d3[0] + x1[1] * d3[1] + x1[2] * d3[2];
  __syncthreads();
  if (threadIdx.x < 32) {
    int oo = threadIdx.x;
    float bd = -INFINITY; int wp_ = 0;
#pragma unroll
    for (int p2 = 0; p2 < 4; ++p2) {
      float dv = dlds[p2][oo];
      if (dv > bd) { bd = dv; wp_ = p2; }     // strict '>': first n wins
    }
    float4 xv = x1lds[wp_][oo];
    partials[(size_t)(bk * 512 + pb) * 32 + oo] = make_float4(xv.x, xv.y, xv.z, bd);
  }
}

// ---------------------------------------------------------------------------
// Kernel 3: per (bk,o): argmax over 512 block-partials (first-index ties),
// write winning x1 vector.
// ---------------------------------------------------------------------------
__global__ __launch_bounds__(256) void pool_kernel(
    const float4* __restrict__ partials, float* __restrict__ pooled) {
  int pair = blockIdx.x * 4 + (threadIdx.x >> 6);   // 512 (bk,o) pairs
  int lane = threadIdx.x & 63;
  int bk = pair >> 5, o = pair & 31;
  const float* pf = (const float*)partials;
  float best = -INFINITY; int bp = 0x7fffffff;
  for (int t = 0; t < 8; ++t) {
    int pb = t * 64 + lane;
    float v = pf[((size_t)(bk * 512 + pb) * 32 + o) * 4 + 3];
    if (v > best) { best = v; bp = pb; }
  }
#pragma unroll
  for (int off = 1; off < 64; off <<= 1) {
    float ov = __shfl_xor(best, off);
    int   op = __shfl_xor(bp, off);
    if (ov > best || (ov == best && op < bp)) { best = ov; bp = op; }
  }
  if (lane == 0) {
    float4 xv = partials[(size_t)(bk * 512 + bp) * 32 + o];
    pooled[(bk * 32 + o) * 3 + 0] = xv.x;
    pooled[(bk * 32 + o) * 3 + 1] = xv.y;
    pooled[(bk * 32 + o) * 3 + 2] = xv.z;
  }
}

// ---------------------------------------------------------------------------
// Kernel 4: pk = Wh2 @ pooled ; +GS_EPS*noise ; Gram-Schmidt ; det flip
// ---------------------------------------------------------------------------
__global__ __launch_bounds__(64) void head_kernel(
    const float* __restrict__ pooled, const float* __restrict__ Wh2,
    const float* __restrict__ gs, float* __restrict__ out) {
  int bk = threadIdx.x;
  if (bk >= BKT) return;
  float M[3][3];
#pragma unroll
  for (int oo = 0; oo < 3; ++oo) {
    float a0 = 0.f, a1 = 0.f, a2 = 0.f;
    for (int c = 0; c < 32; ++c) {
      float w = Wh2[oo * 32 + c];
      a0 = fmaf(w, pooled[(bk * 32 + c) * 3 + 0], a0);
      a1 = fmaf(w, pooled[(bk * 32 + c) * 3 + 1], a1);
      a2 = fmaf(w, pooled[(bk * 32 + c) * 3 + 2], a2);
    }
    M[0][oo] = a0 + GS_EPSF * gs[bk * 9 + 0 * 3 + oo];
    M[1][oo] = a1 + GS_EPSF * gs[bk * 9 + 1 * 3 + oo];
    M[2][oo] = a2 + GS_EPSF * gs[bk * 9 + 2 * 3 + oo];
  }
  float e1[3], e2[3], e3[3], u[3];
  float nn = sqrtf(M[0][0] * M[0][0] + M[1][0] * M[1][0] + M[2][0] * M[2][0]) + EPSF;
#pragma unroll
  for (int r = 0; r < 3; ++r) e1[r] = M[r][0] / nn;
  float d12 = e1[0] * M[0][1] + e1[1] * M[1][1] + e1[2] * M[2][1];
#pragma unroll
  for (int r = 0; r < 3; ++r) u[r] = M[r][1] - d12 * e1[r];
  nn = sqrtf(u[0] * u[0] + u[1] * u[1] + u[2] * u[2]) + EPSF;
#pragma unroll
  for (int r = 0; r < 3; ++r) e2[r] = u[r] / nn;
  float d13 = e1[0] * M[0][2] + e1[1] * M[1][2] + e1[2] * M[2][2];
  float d23 = e2[0] * M[0][2] + e2[1] * M[1][2] + e2[2] * M[2][2];
#pragma unroll
  for (int r = 0; r < 3; ++r) u[r] = M[r][2] - d13 * e1[r] - d23 * e2[r];
  nn = sqrtf(u[0] * u[0] + u[1] * u[1] + u[2] * u[2]) + EPSF;
#pragma unroll
  for (int r = 0; r < 3; ++r) e3[r] = u[r] / nn;
  float det = e1[0] * (e2[1] * e3[2] - e2[2] * e3[1])
            - e1[1] * (e2[0] * e3[2] - e2[2] * e3[0])
            + e1[2] * (e2[0] * e3[1] - e2[1] * e3[0]);
#pragma unroll
  for (int r = 0; r < 3; ++r) {
    out[bk * 9 + r * 3 + 0] = e1[r] * det;
    out[bk * 9 + r * 3 + 1] = e2[r];
    out[bk * 9 + r * 3 + 2] = e3[r];
  }
}

// ---------------------------------------------------------------------------
extern "C" void kernel_launch(void* const* d_in, const int* in_sizes, int n_in,
                              void* d_out, int out_size, void* d_ws, size_t ws_size,
                              hipStream_t stream) {
  (void)in_sizes; (void)n_in; (void)out_size; (void)ws_size;
  const float* node = (const float*)d_in[0];
  const float* W1f = (const float*)d_in[4];
  const float* W1d = (const float*)d_in[5];
  const float* Wp1 = (const float*)d_in[6];
  const float* Wp3 = (const float*)d_in[7];
  const float* Wh2 = (const float*)d_in[8];
  const float* z   = (const float*)d_in[9];
  const float* gs  = (const float*)d_in[10];

  float4* cA       = (float4*)d_ws;                       // 32768 f4 = 512 KB
  float4* cB       = cA + BKT * NPT;                      // 512 KB
  int4*   knn4     = (int4*)(cB + BKT * NPT);             // 512 KB
  float4* partials = (float4*)(knn4 + BKT * NPT);         // 16*512*32 f4 = 4 MB
  float*  pooled   = (float*)(partials + BKT * 512 * 32); // 1536 f
  float*  out      = (float*)d_out;

  prep_coords   <<<BKT * NPT / 256, 256, 0, stream>>>(node, z, cA, cB);
  knn_kernel    <<<BKT * (NPT / 64), 256, 0, stream>>>(cA, cB, knn4);
  feature_kernel<<<BKT * NPT / 4, 128, 0, stream>>>(cA, cB, knn4, W1f, W1d, Wp1, Wp3, partials);
  pool_kernel   <<<512 / 4, 256, 0, stream>>>(partials, pooled);
  head_kernel   <<<1, 64, 0, stream>>>(pooled, Wh2, gs, out);
}

// Round 3
// 128.376 us; speedup vs baseline: 2.2768x; 2.2768x over previous
//
#include <hip/hip_runtime.h>
#include <math.h>

#define EPSF    1e-8f
#define SLOPEF  0.2f
#define GS_EPSF 1e-6f

#define NB   4
#define KZ   4
#define BKT  16     // NB*KZ
#define NPT  2048
#define DIM  32

// ---------------------------------------------------------------------------
// Kernel 0: pts[bk*2048+n] = {A=(ch0,ch1,ch2,ch3), B=(ch4,ch5,xx,0)} interleaved
// ---------------------------------------------------------------------------
__global__ __launch_bounds__(256) void prep_coords(
    const float* __restrict__ node, const float* __restrict__ z,
    float4* __restrict__ pts) {
  int t = blockIdx.x * 256 + threadIdx.x;
  if (t >= BKT * NPT) return;
  int bk = t >> 11, n = t & (NPT - 1);
  int b = bk >> 2, kz = bk & 3;
  const float2* np2 = (const float2*)(node + (size_t)(b * NPT + n) * 6);
  const float2* zp2 = (const float2*)(z + (size_t)((b * KZ + kz) * NPT + n) * 6);
  float ch[6];
#pragma unroll
  for (int j = 0; j < 3; ++j) {
    float2 a = np2[j], c = zp2[j];
    ch[j]     = a.x + c.x;
    ch[3 + j] = a.y + c.y;
  }
  float xx = 0.f;
#pragma unroll
  for (int h = 0; h < 6; ++h) xx = fmaf(ch[h], ch[h], xx);
  pts[(size_t)t * 2 + 0] = make_float4(ch[0], ch[1], ch[2], ch[3]);
  pts[(size_t)t * 2 + 1] = make_float4(ch[4], ch[5], xx, 0.f);
}

// ---------------------------------------------------------------------------
// branchless sorted-insert (desc). Scan is ascending-j with strict '>', so
// equal values never displace -> first-index semantics, no idx compares.
// ---------------------------------------------------------------------------
__device__ __forceinline__ void ins4(float s, int j,
    float& v0, float& v1, float& v2, float& v3,
    int& i0, int& i1, int& i2, int& i3) {
  bool c3 = s > v3;
  float nv3 = c3 ? s : v3; int ni3 = c3 ? j : i3;
  bool c2 = nv3 > v2;
  float t2v = c2 ? nv3 : v2, t3v = c2 ? v2 : nv3;
  int   t2i = c2 ? ni3 : i2, t3i = c2 ? i2 : ni3;
  bool c1 = t2v > v1;
  float u1v = c1 ? t2v : v1, u2v = c1 ? v1 : t2v;
  int   u1i = c1 ? t2i : i1, u2i = c1 ? i1 : t2i;
  bool c0 = u1v > v0;
  v1 = c0 ? v0 : u1v; i1 = c0 ? i0 : u1i;
  v0 = c0 ? u1v : v0; i0 = c0 ? u1i : i0;
  v2 = u2v; i2 = u2i; v3 = t3v; i3 = t3i;
}

// compare-exchange for merges: total order (value desc, index asc)
__device__ __forceinline__ void ce(float& vx, int& ix, float& vy, int& iy) {
  float av = vx, bv = vy; int ai = ix, bi = iy;
  bool sw = (bv > av) || (bv == av && bi < ai);
  vx = sw ? bv : av; vy = sw ? av : bv;
  ix = sw ? bi : ai; iy = sw ? ai : bi;
}

__device__ __forceinline__ float score7(const float4& qa, const float4& qb,
                                        const float4& A, const float4& B) {
  float s = qa.x * A.x;
  s = fmaf(qa.y, A.y, s);
  s = fmaf(qa.z, A.z, s);
  s = fmaf(qa.w, A.w, s);
  s = fmaf(qb.x, B.x, s);
  s = fmaf(qb.y, B.y, s);
  s = fmaf(-0.5f, B.z, s);
  return s;
}

// ---------------------------------------------------------------------------
// Kernel 1a: partial top-4. Block = 64 queries x 4 waves; wave w scans segment
// seg = (blk&3)*4+w of 128 points (wave-uniform addresses). In-block merge of
// the 4 wave lists -> pv/pi[(bk*2048+q)*4 + sg].
// ---------------------------------------------------------------------------
__global__ __launch_bounds__(256) void knn_part(
    const float4* __restrict__ pts,
    float4* __restrict__ pv, int4* __restrict__ pi) {
  __shared__ float4 lv[4][64];
  __shared__ int4   li[4][64];
  int lane = threadIdx.x & 63;
  int w = threadIdx.x >> 6;
  int b = blockIdx.x;
  int sg = b & 3, qg = (b >> 2) & 31, bk = b >> 7;
  int base = bk * NPT;
  int q = qg * 64 + lane;
  float4 qa = pts[(size_t)(base + q) * 2 + 0];
  float4 qb = pts[(size_t)(base + q) * 2 + 1];
  int j0 = __builtin_amdgcn_readfirstlane((sg * 4 + w) * 128);
  const float4* pp = pts + ((size_t)base + j0) * 2;
  float v0 = -INFINITY, v1 = -INFINITY, v2 = -INFINITY, v3 = -INFINITY;
  int   i0 = 0x7fffffff, i1 = 0x7fffffff, i2 = 0x7fffffff, i3 = 0x7fffffff;
  for (int t = 0; t < 128; t += 4) {
    float4 A0 = pp[2 * t + 0], B0 = pp[2 * t + 1];
    float4 A1 = pp[2 * t + 2], B1 = pp[2 * t + 3];
    float4 A2 = pp[2 * t + 4], B2 = pp[2 * t + 5];
    float4 A3 = pp[2 * t + 6], B3 = pp[2 * t + 7];
    float s0 = score7(qa, qb, A0, B0);
    float s1 = score7(qa, qb, A1, B1);
    float s2 = score7(qa, qb, A2, B2);
    float s3 = score7(qa, qb, A3, B3);
    ins4(s0, j0 + t + 0, v0, v1, v2, v3, i0, i1, i2, i3);
    ins4(s1, j0 + t + 1, v0, v1, v2, v3, i0, i1, i2, i3);
    ins4(s2, j0 + t + 2, v0, v1, v2, v3, i0, i1, i2, i3);
    ins4(s3, j0 + t + 3, v0, v1, v2, v3, i0, i1, i2, i3);
  }
  lv[w][lane] = make_float4(v0, v1, v2, v3);
  li[w][lane] = make_int4(i0, i1, i2, i3);
  __syncthreads();
  if (w == 0) {
#pragma unroll
    for (int ww = 1; ww < 4; ++ww) {
      float4 bv = lv[ww][lane]; int4 bi = li[ww][lane];
      float s4 = bv.w, s5 = bv.z, s6 = bv.y, s7 = bv.x;
      int   t4 = bi.w, t5 = bi.z, t6 = bi.y, t7 = bi.x;
      ce(v0, i0, s4, t4); ce(v1, i1, s5, t5);
      ce(v2, i2, s6, t6); ce(v3, i3, s7, t7);
      ce(v0, i0, v2, i2); ce(v1, i1, v3, i3);
      ce(v0, i0, v1, i1); ce(v2, i2, v3, i3);
    }
    pv[(size_t)(base + q) * 4 + sg] = make_float4(v0, v1, v2, v3);
    pi[(size_t)(base + q) * 4 + sg] = make_int4(i0, i1, i2, i3);
  }
}

// ---------------------------------------------------------------------------
// Kernel 1b: merge the 4 segment-group partials per query -> knn4
// ---------------------------------------------------------------------------
__global__ __launch_bounds__(256) void knn_merge(
    const float4* __restrict__ pv, const int4* __restrict__ pi,
    int4* __restrict__ knn4) {
  int t = blockIdx.x * 256 + threadIdx.x;
  if (t >= BKT * NPT) return;
  float4 av = pv[(size_t)t * 4]; int4 ai = pi[(size_t)t * 4];
  float v0 = av.x, v1 = av.y, v2 = av.z, v3 = av.w;
  int   i0 = ai.x, i1 = ai.y, i2 = ai.z, i3 = ai.w;
#pragma unroll
  for (int sg = 1; sg < 4; ++sg) {
    float4 bv = pv[(size_t)t * 4 + sg]; int4 bi = pi[(size_t)t * 4 + sg];
    float s4 = bv.w, s5 = bv.z, s6 = bv.y, s7 = bv.x;
    int   t4 = bi.w, t5 = bi.z, t6 = bi.y, t7 = bi.x;
    ce(v0, i0, s4, t4); ce(v1, i1, s5, t5);
    ce(v2, i2, s6, t6); ce(v3, i3, s7, t7);
    ce(v0, i0, v2, i2); ce(v1, i1, v3, i3);
    ce(v0, i0, v1, i1); ce(v2, i2, v3, i3);
  }
  knn4[t] = make_int4(i0, i1, i2, i3);
}

// ---------------------------------------------------------------------------
// Kernel 2: per point: G -> p,d -> leaky -> h; pool over k -> x1; dot3;
// in-block argmax over 4 points -> partials[bk][pb][o] = (x1, dot3)
// ---------------------------------------------------------------------------
__global__ __launch_bounds__(128) void feature_kernel(
    const float4* __restrict__ pts, const int4* __restrict__ knn4,
    const float* __restrict__ W1f, const float* __restrict__ W1d,
    const float* __restrict__ Wp1, const float* __restrict__ Wp3,
    float4* __restrict__ partials) {
  __shared__ float4 hlds[4][4][DIM];
  __shared__ float4 x1lds[4][DIM];
  __shared__ float  dlds[4][DIM];
  __shared__ float  wp1T[DIM * DIM], wp3T[DIM * DIM];
  for (int i = threadIdx.x; i < DIM * DIM; i += 128) {
    int o = i & 31, c = i >> 5;
    wp1T[i] = Wp1[o * 32 + c];
    wp3T[i] = Wp3[o * 32 + c];
  }
  int p = threadIdx.x >> 5, o = threadIdx.x & 31;
  int bk = blockIdx.x >> 9, pb = blockIdx.x & 511;
  int n = (pb << 2) | p;
  int base = bk * NPT;
  float4 ca = pts[(size_t)(base + n) * 2 + 0], cb = pts[(size_t)(base + n) * 2 + 1];
  float ct[6] = {ca.x, ca.y, ca.z, ca.w, cb.x, cb.y};
  float4 wf = reinterpret_cast<const float4*>(W1f)[o];
  float4 wd = reinterpret_cast<const float4*>(W1d)[o];
  float w1f[4] = {wf.x, wf.y, wf.z, wf.w};
  float w1d[4] = {wd.x, wd.y, wd.z, wd.w};
  int4 nb = knn4[base + n];
  int nbi[4] = {nb.x, nb.y, nb.z, nb.w};
  float h[4][3];
#pragma unroll
  for (int kk = 0; kk < 4; ++kk) {
    int m = nbi[kk];
    float4 A = pts[(size_t)(base + m) * 2 + 0], B = pts[(size_t)(base + m) * 2 + 1];
    float nc[6] = {A.x, A.y, A.z, A.w, B.x, B.y};
    float G[4][3];
#pragma unroll
    for (int j = 0; j < 3; ++j) {
      G[0][j] = nc[j] - ct[j];
      G[1][j] = nc[3 + j] - ct[3 + j];
      G[2][j] = ct[j];
      G[3][j] = ct[3 + j];
    }
    float pvv[3], dv[3];
#pragma unroll
    for (int j = 0; j < 3; ++j) {
      float a = 0.f, dd = 0.f;
#pragma unroll
      for (int c = 0; c < 4; ++c) { a = fmaf(w1f[c], G[c][j], a); dd = fmaf(w1d[c], G[c][j], dd); }
      pvv[j] = a; dv[j] = dd;
    }
    float dot = pvv[0] * dv[0] + pvv[1] * dv[1] + pvv[2] * dv[2];
    float d2  = dv[0] * dv[0] + dv[1] * dv[1] + dv[2] * dv[2];
    float fac = dot / (d2 + EPSF);
#pragma unroll
    for (int j = 0; j < 3; ++j) {
      float negj = pvv[j] - fac * dv[j];
      float sel = (dot >= 0.f) ? pvv[j] : negj;
      h[kk][j] = SLOPEF * pvv[j] + (1.f - SLOPEF) * sel;
    }
    hlds[p][kk][o] = make_float4(h[kk][0], h[kk][1], h[kk][2], 0.f);
  }
  __syncthreads();
  float d1[4][3] = {};
  for (int c = 0; c < 32; ++c) {
    float wp = wp1T[c * 32 + o];
#pragma unroll
    for (int kk = 0; kk < 4; ++kk) {
      float4 hv = hlds[p][kk][c];
      d1[kk][0] = fmaf(wp, hv.x, d1[kk][0]);
      d1[kk][1] = fmaf(wp, hv.y, d1[kk][1]);
      d1[kk][2] = fmaf(wp, hv.z, d1[kk][2]);
    }
  }
  float best = -INFINITY;
  float x1[3] = {0.f, 0.f, 0.f};
#pragma unroll
  for (int kk = 0; kk < 4; ++kk) {
    float dt = h[kk][0] * d1[kk][0] + h[kk][1] * d1[kk][1] + h[kk][2] * d1[kk][2];
    if (dt > best) { best = dt; x1[0] = h[kk][0]; x1[1] = h[kk][1]; x1[2] = h[kk][2]; }
  }
  x1lds[p][o] = make_float4(x1[0], x1[1], x1[2], 0.f);
  __syncthreads();
  float d3[3] = {0.f, 0.f, 0.f};
  for (int c = 0; c < 32; ++c) {
    float wp = wp3T[c * 32 + o];
    float4 xv = x1lds[p][c];
    d3[0] = fmaf(wp, xv.x, d3[0]);
    d3[1] = fmaf(wp, xv.y, d3[1]);
    d3[2] = fmaf(wp, xv.z, d3[2]);
  }
  dlds[p][o] = x1[0] * d3[0] + x1[1] * d3[1] + x1[2] * d3[2];
  __syncthreads();
  if (threadIdx.x < 32) {
    int oo = threadIdx.x;
    float bd = -INFINITY; int wp_ = 0;
#pragma unroll
    for (int p2 = 0; p2 < 4; ++p2) {
      float dv = dlds[p2][oo];
      if (dv > bd) { bd = dv; wp_ = p2; }
    }
    float4 xv = x1lds[wp_][oo];
    partials[(size_t)(bk * 512 + pb) * 32 + oo] = make_float4(xv.x, xv.y, xv.z, bd);
  }
}

// ---------------------------------------------------------------------------
// Kernel 3: per (bk,o): argmax over 512 block-partials (first-index ties)
// ---------------------------------------------------------------------------
__global__ __launch_bounds__(256) void pool_kernel(
    const float4* __restrict__ partials, float* __restrict__ pooled) {
  int pair = blockIdx.x * 4 + (threadIdx.x >> 6);
  int lane = threadIdx.x & 63;
  int bk = pair >> 5, o = pair & 31;
  const float* pf = (const float*)partials;
  float best = -INFINITY; int bp = 0x7fffffff;
  for (int t = 0; t < 8; ++t) {
    int pb = t * 64 + lane;
    float v = pf[((size_t)(bk * 512 + pb) * 32 + o) * 4 + 3];
    if (v > best) { best = v; bp = pb; }
  }
#pragma unroll
  for (int off = 1; off < 64; off <<= 1) {
    float ov = __shfl_xor(best, off);
    int   op = __shfl_xor(bp, off);
    if (ov > best || (ov == best && op < bp)) { best = ov; bp = op; }
  }
  if (lane == 0) {
    float4 xv = partials[(size_t)(bk * 512 + bp) * 32 + o];
    pooled[(bk * 32 + o) * 3 + 0] = xv.x;
    pooled[(bk * 32 + o) * 3 + 1] = xv.y;
    pooled[(bk * 32 + o) * 3 + 2] = xv.z;
  }
}

// ---------------------------------------------------------------------------
// Kernel 4: pk = Wh2 @ pooled ; +GS_EPS*noise ; Gram-Schmidt ; det flip
// ---------------------------------------------------------------------------
__global__ __launch_bounds__(64) void head_kernel(
    const float* __restrict__ pooled, const float* __restrict__ Wh2,
    const float* __restrict__ gs, float* __restrict__ out) {
  int bk = threadIdx.x;
  if (bk >= BKT) return;
  float M[3][3];
#pragma unroll
  for (int oo = 0; oo < 3; ++oo) {
    float a0 = 0.f, a1 = 0.f, a2 = 0.f;
    for (int c = 0; c < 32; ++c) {
      float w = Wh2[oo * 32 + c];
      a0 = fmaf(w, pooled[(bk * 32 + c) * 3 + 0], a0);
      a1 = fmaf(w, pooled[(bk * 32 + c) * 3 + 1], a1);
      a2 = fmaf(w, pooled[(bk * 32 + c) * 3 + 2], a2);
    }
    M[0][oo] = a0 + GS_EPSF * gs[bk * 9 + 0 * 3 + oo];
    M[1][oo] = a1 + GS_EPSF * gs[bk * 9 + 1 * 3 + oo];
    M[2][oo] = a2 + GS_EPSF * gs[bk * 9 + 2 * 3 + oo];
  }
  float e1[3], e2[3], e3[3], u[3];
  float nn = sqrtf(M[0][0] * M[0][0] + M[1][0] * M[1][0] + M[2][0] * M[2][0]) + EPSF;
#pragma unroll
  for (int r = 0; r < 3; ++r) e1[r] = M[r][0] / nn;
  float d12 = e1[0] * M[0][1] + e1[1] * M[1][1] + e1[2] * M[2][1];
#pragma unroll
  for (int r = 0; r < 3; ++r) u[r] = M[r][1] - d12 * e1[r];
  nn = sqrtf(u[0] * u[0] + u[1] * u[1] + u[2] * u[2]) + EPSF;
#pragma unroll
  for (int r = 0; r < 3; ++r) e2[r] = u[r] / nn;
  float d13 = e1[0] * M[0][2] + e1[1] * M[1][2] + e1[2] * M[2][2];
  float d23 = e2[0] * M[0][2] + e2[1] * M[1][2] + e2[2] * M[2][2];
#pragma unroll
  for (int r = 0; r < 3; ++r) u[r] = M[r][2] - d13 * e1[r] - d23 * e2[r];
  nn = sqrtf(u[0] * u[0] + u[1] * u[1] + u[2] * u[2]) + EPSF;
#pragma unroll
  for (int r = 0; r < 3; ++r) e3[r] = u[r] / nn;
  float det = e1[0] * (e2[1] * e3[2] - e2[2] * e3[1])
            - e1[1] * (e2[0] * e3[2] - e2[2] * e3[0])
            + e1[2] * (e2[0] * e3[1] - e2[1] * e3[0]);
#pragma unroll
  for (int r = 0; r < 3; ++r) {
    out[bk * 9 + r * 3 + 0] = e1[r] * det;
    out[bk * 9 + r * 3 + 1] = e2[r];
    out[bk * 9 + r * 3 + 2] = e3[r];
  }
}

// ---------------------------------------------------------------------------
extern "C" void kernel_launch(void* const* d_in, const int* in_sizes, int n_in,
                              void* d_out, int out_size, void* d_ws, size_t ws_size,
                              hipStream_t stream) {
  (void)in_sizes; (void)n_in; (void)out_size; (void)ws_size;
  const float* node = (const float*)d_in[0];
  const float* W1f = (const float*)d_in[4];
  const float* W1d = (const float*)d_in[5];
  const float* Wp1 = (const float*)d_in[6];
  const float* Wp3 = (const float*)d_in[7];
  const float* Wh2 = (const float*)d_in[8];
  const float* z   = (const float*)d_in[9];
  const float* gs  = (const float*)d_in[10];

  float4* pts      = (float4*)d_ws;                        // 32768*2 f4 = 1 MB
  float4* pv       = pts + (size_t)BKT * NPT * 2;          // 32768*4 f4 = 2 MB
  int4*   pi       = (int4*)(pv + (size_t)BKT * NPT * 4);  // 2 MB
  int4*   knn4     = pi + (size_t)BKT * NPT * 4;           // 512 KB
  float4* partials = (float4*)(knn4 + (size_t)BKT * NPT);  // 16*512*32 f4 = 4 MB
  float*  pooled   = (float*)(partials + (size_t)BKT * 512 * 32); // 1536 f
  float*  out      = (float*)d_out;

  prep_coords   <<<BKT * NPT / 256, 256, 0, stream>>>(node, z, pts);
  knn_part      <<<BKT * 32 * 4, 256, 0, stream>>>(pts, pv, pi);
  knn_merge     <<<BKT * NPT / 256, 256, 0, stream>>>(pv, pi, knn4);
  feature_kernel<<<BKT * NPT / 4, 128, 0, stream>>>(pts, knn4, W1f, W1d, Wp1, Wp3, partials);
  pool_kernel   <<<512 / 4, 256, 0, stream>>>(partials, pooled);
  head_kernel   <<<1, 64, 0, stream>>>(pooled, Wh2, gs, out);
}

// Round 4
// 103.190 us; speedup vs baseline: 2.8325x; 1.2441x over previous
//
#include <hip/hip_runtime.h>
#include <math.h>

#define EPSF    1e-8f
#define SLOPEF  0.2f
#define GS_EPSF 1e-6f

#define NB   4
#define KZ   4
#define BKT  16     // NB*KZ
#define NPT  2048
#define DIM  32

// ---------------------------------------------------------------------------
// Kernel 0: pts[bk*2048+n] = {A=(ch0,ch1,ch2,ch3), B=(ch4,ch5,xx,0)} interleaved
// ---------------------------------------------------------------------------
__global__ __launch_bounds__(256) void prep_coords(
    const float* __restrict__ node, const float* __restrict__ z,
    float4* __restrict__ pts) {
  int t = blockIdx.x * 256 + threadIdx.x;
  if (t >= BKT * NPT) return;
  int bk = t >> 11, n = t & (NPT - 1);
  int b = bk >> 2, kz = bk & 3;
  const float2* np2 = (const float2*)(node + (size_t)(b * NPT + n) * 6);
  const float2* zp2 = (const float2*)(z + (size_t)((b * KZ + kz) * NPT + n) * 6);
  float ch[6];
#pragma unroll
  for (int j = 0; j < 3; ++j) {
    float2 a = np2[j], c = zp2[j];
    ch[j]     = a.x + c.x;
    ch[3 + j] = a.y + c.y;
  }
  float xx = 0.f;
#pragma unroll
  for (int h = 0; h < 6; ++h) xx = fmaf(ch[h], ch[h], xx);
  pts[(size_t)t * 2 + 0] = make_float4(ch[0], ch[1], ch[2], ch[3]);
  pts[(size_t)t * 2 + 1] = make_float4(ch[4], ch[5], xx, 0.f);
}

// ---------------------------------------------------------------------------
// branchless sorted-insert of (s,j) into desc top-3. Ascending-j scan + strict
// '>' => first-index semantics without index compares.
// ---------------------------------------------------------------------------
__device__ __forceinline__ void ins3(float s, int j,
    float& v0, float& v1, float& v2, int& i0, int& i1, int& i2) {
  bool c2 = s > v2;
  float nv2 = c2 ? s : v2; int ni2 = c2 ? j : i2;
  bool c1 = nv2 > v1;
  float u1v = c1 ? nv2 : v1, u2v = c1 ? v1 : nv2;
  int   u1i = c1 ? ni2 : i1, u2i = c1 ? i1 : ni2;
  bool c0 = u1v > v0;
  v1 = c0 ? v0 : u1v; i1 = c0 ? i0 : u1i;
  v0 = c0 ? u1v : v0; i0 = c0 ? u1i : i0;
  v2 = u2v; i2 = u2i;
}

// compare-exchange: total order (value desc, index asc)
__device__ __forceinline__ void ce(float& vx, int& ix, float& vy, int& iy) {
  float av = vx, bv = vy; int ai = ix, bi = iy;
  bool sw = (bv > av) || (bv == av && bi < ai);
  vx = sw ? bv : av; vy = sw ? av : bv;
  ix = sw ? bi : ai; iy = sw ? ai : bi;
}

__device__ __forceinline__ float score7(const float4& qa, const float4& qb,
                                        const float4& A, const float4& B) {
  float s = qa.x * A.x;
  s = fmaf(qa.y, A.y, s);
  s = fmaf(qa.z, A.z, s);
  s = fmaf(qa.w, A.w, s);
  s = fmaf(qb.x, B.x, s);
  s = fmaf(qb.y, B.y, s);
  s = fmaf(-0.5f, B.z, s);
  return s;
}

template <bool SELF>
__device__ __forceinline__ void scan256(const float4* __restrict__ pp, int j0, int q,
    const float4 qa, const float4 qb,
    float& v0, float& v1, float& v2, int& i0, int& i1, int& i2) {
  for (int t = 0; t < 256; t += 4) {
    float4 A0 = pp[2 * t + 0], B0 = pp[2 * t + 1];
    float4 A1 = pp[2 * t + 2], B1 = pp[2 * t + 3];
    float4 A2 = pp[2 * t + 4], B2 = pp[2 * t + 5];
    float4 A3 = pp[2 * t + 6], B3 = pp[2 * t + 7];
    float s0 = score7(qa, qb, A0, B0);
    float s1 = score7(qa, qb, A1, B1);
    float s2 = score7(qa, qb, A2, B2);
    float s3 = score7(qa, qb, A3, B3);
    int jb = j0 + t;
    if (SELF) {
      if (jb + 0 == q) s0 = -INFINITY;
      if (jb + 1 == q) s1 = -INFINITY;
      if (jb + 2 == q) s2 = -INFINITY;
      if (jb + 3 == q) s3 = -INFINITY;
    }
    ins3(s0, jb + 0, v0, v1, v2, i0, i1, i2);
    ins3(s1, jb + 1, v0, v1, v2, i0, i1, i2);
    ins3(s2, jb + 2, v0, v1, v2, i0, i1, i2);
    ins3(s3, jb + 3, v0, v1, v2, i0, i1, i2);
  }
}

// ---------------------------------------------------------------------------
// Kernel 1: full KNN in one block. Block = 64 queries x 8 waves; wave w scans
// 256-point segment w (wave-uniform addresses). Self (dist 0) is always the
// top-1 -> scan top-3 of j!=q, prepend q. LDS tree merge -> knn4 directly.
// ---------------------------------------------------------------------------
__global__ __launch_bounds__(512) void knn_kernel(
    const float4* __restrict__ pts, int4* __restrict__ knn4) {
  __shared__ float4 lv[8][64];
  __shared__ int4   li[8][64];
  int lane = threadIdx.x & 63;
  int w = threadIdx.x >> 6;                 // segment 0..7
  int bk = blockIdx.x >> 5, qg = blockIdx.x & 31;
  int base = bk * NPT;
  int q = qg * 64 + lane;
  float4 qa = pts[(size_t)(base + q) * 2 + 0];
  float4 qb = pts[(size_t)(base + q) * 2 + 1];
  int j0 = __builtin_amdgcn_readfirstlane(w * 256);
  const float4* pp = pts + ((size_t)base + j0) * 2;
  float v0 = -INFINITY, v1 = -INFINITY, v2 = -INFINITY;
  int   i0 = 0x7fffffff, i1 = 0x7fffffff, i2 = 0x7fffffff;
  if (w == (qg >> 2)) scan256<true >(pp, j0, q, qa, qb, v0, v1, v2, i0, i1, i2);
  else                scan256<false>(pp, j0, q, qa, qb, v0, v1, v2, i0, i1, i2);
  lv[w][lane] = make_float4(v0, v1, v2, -INFINITY);
  li[w][lane] = make_int4(i0, i1, i2, 0x7fffffff);
  __syncthreads();
#pragma unroll
  for (int str = 4; str >= 1; str >>= 1) {
    if (w < str) {
      float4 av = lv[w][lane];        int4 ai = li[w][lane];
      float4 bv = lv[w + str][lane];  int4 bi = li[w + str][lane];
      float a0 = av.x, a1 = av.y, a2 = av.z, a3 = av.w;
      int   c0 = ai.x, c1 = ai.y, c2 = ai.z, c3 = ai.w;
      float s4 = bv.w, s5 = bv.z, s6 = bv.y, s7 = bv.x;
      int   t4 = bi.w, t5 = bi.z, t6 = bi.y, t7 = bi.x;
      ce(a0, c0, s4, t4); ce(a1, c1, s5, t5);
      ce(a2, c2, s6, t6); ce(a3, c3, s7, t7);
      ce(a0, c0, a2, c2); ce(a1, c1, a3, c3);
      ce(a0, c0, a1, c1); ce(a2, c2, a3, c3);
      lv[w][lane] = make_float4(a0, a1, a2, a3);
      li[w][lane] = make_int4(c0, c1, c2, c3);
    }
    __syncthreads();
  }
  if (w == 0) {
    int4 r = li[0][lane];
    knn4[base + q] = make_int4(q, r.x, r.y, r.z);
  }
}

// ---------------------------------------------------------------------------
// Kernel 2: 8 points/block, thread = (p, og) handling o = og and og+16.
// h -> d1 -> argmax over k -> x1 -> d3 -> dot3 -> in-block argmax over 8 pts
// -> partials[bk][o][pb] = (x1, dot3)   (o-major for coalesced pooling)
// ---------------------------------------------------------------------------
__global__ __launch_bounds__(128) void feature_kernel(
    const float4* __restrict__ pts, const int4* __restrict__ knn4,
    const float* __restrict__ W1f, const float* __restrict__ W1d,
    const float* __restrict__ Wp1, const float* __restrict__ Wp3,
    float4* __restrict__ partials) {
  __shared__ float4 hlds[8][4][DIM + 1];
  __shared__ float4 x1lds[8][DIM + 1];
  __shared__ float  dlds[8][DIM + 1];
  __shared__ float  wp1T[DIM * DIM], wp3T[DIM * DIM];   // [c][o]
  for (int i = threadIdx.x; i < DIM * DIM; i += 128) {
    int o = i & 31, c = i >> 5;
    wp1T[i] = Wp1[o * 32 + c];
    wp3T[i] = Wp3[o * 32 + c];
  }
  int p = threadIdx.x >> 4;        // 0..7
  int og = threadIdx.x & 15;       // o = og, og+16
  int bk = blockIdx.x >> 8, pb = blockIdx.x & 255;
  int n = (pb << 3) | p;
  int base = bk * NPT;
  float4 ca = pts[(size_t)(base + n) * 2 + 0], cbv = pts[(size_t)(base + n) * 2 + 1];
  float ct[6] = {ca.x, ca.y, ca.z, ca.w, cbv.x, cbv.y};
  float4 wfA = reinterpret_cast<const float4*>(W1f)[og];
  float4 wfB = reinterpret_cast<const float4*>(W1f)[og + 16];
  float4 wdA = reinterpret_cast<const float4*>(W1d)[og];
  float4 wdB = reinterpret_cast<const float4*>(W1d)[og + 16];
  float w1f[2][4] = {{wfA.x, wfA.y, wfA.z, wfA.w}, {wfB.x, wfB.y, wfB.z, wfB.w}};
  float w1d[2][4] = {{wdA.x, wdA.y, wdA.z, wdA.w}, {wdB.x, wdB.y, wdB.z, wdB.w}};
  int4 nb = knn4[base + n];
  int nbi[4] = {nb.x, nb.y, nb.z, nb.w};
  float h[2][4][3];
#pragma unroll
  for (int kk = 0; kk < 4; ++kk) {
    int m = nbi[kk];
    float4 A = pts[(size_t)(base + m) * 2 + 0], B = pts[(size_t)(base + m) * 2 + 1];
    float nc[6] = {A.x, A.y, A.z, A.w, B.x, B.y};
    float G[4][3];
#pragma unroll
    for (int j = 0; j < 3; ++j) {
      G[0][j] = nc[j] - ct[j];
      G[1][j] = nc[3 + j] - ct[3 + j];
      G[2][j] = ct[j];
      G[3][j] = ct[3 + j];
    }
#pragma unroll
    for (int oo = 0; oo < 2; ++oo) {
      float pvv[3], dv[3];
#pragma unroll
      for (int j = 0; j < 3; ++j) {
        float a = 0.f, dd = 0.f;
#pragma unroll
        for (int c = 0; c < 4; ++c) { a = fmaf(w1f[oo][c], G[c][j], a); dd = fmaf(w1d[oo][c], G[c][j], dd); }
        pvv[j] = a; dv[j] = dd;
      }
      float dot = pvv[0] * dv[0] + pvv[1] * dv[1] + pvv[2] * dv[2];
      float d2  = dv[0] * dv[0] + dv[1] * dv[1] + dv[2] * dv[2];
      float fac = dot / (d2 + EPSF);
#pragma unroll
      for (int j = 0; j < 3; ++j) {
        float negj = pvv[j] - fac * dv[j];
        float sel = (dot >= 0.f) ? pvv[j] : negj;
        h[oo][kk][j] = SLOPEF * pvv[j] + (1.f - SLOPEF) * sel;
      }
    }
    hlds[p][kk][og]      = make_float4(h[0][kk][0], h[0][kk][1], h[0][kk][2], 0.f);
    hlds[p][kk][og + 16] = make_float4(h[1][kk][0], h[1][kk][1], h[1][kk][2], 0.f);
  }
  __syncthreads();
  float d1[2][4][3] = {};
  for (int c = 0; c < 32; ++c) {
    float wpa = wp1T[c * 32 + og], wpb = wp1T[c * 32 + og + 16];
#pragma unroll
    for (int kk = 0; kk < 4; ++kk) {
      float4 hv = hlds[p][kk][c];
      d1[0][kk][0] = fmaf(wpa, hv.x, d1[0][kk][0]);
      d1[0][kk][1] = fmaf(wpa, hv.y, d1[0][kk][1]);
      d1[0][kk][2] = fmaf(wpa, hv.z, d1[0][kk][2]);
      d1[1][kk][0] = fmaf(wpb, hv.x, d1[1][kk][0]);
      d1[1][kk][1] = fmaf(wpb, hv.y, d1[1][kk][1]);
      d1[1][kk][2] = fmaf(wpb, hv.z, d1[1][kk][2]);
    }
  }
  float x1[2][3];
#pragma unroll
  for (int oo = 0; oo < 2; ++oo) {
    float best = -INFINITY;
    float xa = 0.f, xb = 0.f, xc = 0.f;
#pragma unroll
    for (int kk = 0; kk < 4; ++kk) {
      float dt = h[oo][kk][0] * d1[oo][kk][0] + h[oo][kk][1] * d1[oo][kk][1] + h[oo][kk][2] * d1[oo][kk][2];
      if (dt > best) { best = dt; xa = h[oo][kk][0]; xb = h[oo][kk][1]; xc = h[oo][kk][2]; }
    }
    x1[oo][0] = xa; x1[oo][1] = xb; x1[oo][2] = xc;
  }
  x1lds[p][og]      = make_float4(x1[0][0], x1[0][1], x1[0][2], 0.f);
  x1lds[p][og + 16] = make_float4(x1[1][0], x1[1][1], x1[1][2], 0.f);
  __syncthreads();
  float d3[2][3] = {};
  for (int c = 0; c < 32; ++c) {
    float wpa = wp3T[c * 32 + og], wpb = wp3T[c * 32 + og + 16];
    float4 xv = x1lds[p][c];
    d3[0][0] = fmaf(wpa, xv.x, d3[0][0]);
    d3[0][1] = fmaf(wpa, xv.y, d3[0][1]);
    d3[0][2] = fmaf(wpa, xv.z, d3[0][2]);
    d3[1][0] = fmaf(wpb, xv.x, d3[1][0]);
    d3[1][1] = fmaf(wpb, xv.y, d3[1][1]);
    d3[1][2] = fmaf(wpb, xv.z, d3[1][2]);
  }
  dlds[p][og]      = x1[0][0] * d3[0][0] + x1[0][1] * d3[0][1] + x1[0][2] * d3[0][2];
  dlds[p][og + 16] = x1[1][0] * d3[1][0] + x1[1][1] * d3[1][1] + x1[1][2] * d3[1][2];
  __syncthreads();
  if (threadIdx.x < 32) {
    int o = threadIdx.x;
    float bd = -INFINITY; int wp_ = 0;
#pragma unroll
    for (int p2 = 0; p2 < 8; ++p2) {
      float dv = dlds[p2][o];
      if (dv > bd) { bd = dv; wp_ = p2; }       // strict '>': first n wins
    }
    float4 xv = x1lds[wp_][o];
    partials[((size_t)(bk * 32 + o) << 8) | pb] = make_float4(xv.x, xv.y, xv.z, bd);
  }
}

// ---------------------------------------------------------------------------
// Kernel 3: per bk: argmax over 256 partials per o (first-index ties), then
// head: pk = Wh2 @ pooled ; +GS_EPS*noise ; Gram-Schmidt ; det flip
// ---------------------------------------------------------------------------
__global__ __launch_bounds__(256) void poolhead_kernel(
    const float4* __restrict__ partials, const float* __restrict__ Wh2,
    const float* __restrict__ gs, float* __restrict__ out) {
  __shared__ float pl[DIM][3];
  int bk = blockIdx.x;
  int o = threadIdx.x >> 3, tg = threadIdx.x & 7;
  const float4* pp = partials + ((size_t)(bk * 32 + o) << 8);
  float best = -INFINITY; int bp = 0x7fffffff;
  for (int t = 0; t < 32; ++t) {
    int pb = t * 8 + tg;                       // interleaved, coalesced
    float v = pp[pb].w;
    if (v > best) { best = v; bp = pb; }       // strict '>': lowest pb in class
  }
#pragma unroll
  for (int off = 1; off < 8; off <<= 1) {
    float ov = __shfl_xor(best, off, 8);
    int   op = __shfl_xor(bp, off, 8);
    if (ov > best || (ov == best && op < bp)) { best = ov; bp = op; }
  }
  if (tg == 0) {
    float4 xv = pp[bp];
    pl[o][0] = xv.x; pl[o][1] = xv.y; pl[o][2] = xv.z;
  }
  __syncthreads();
  if (threadIdx.x == 0) {
    float M[3][3];
#pragma unroll
    for (int oo = 0; oo < 3; ++oo) {
      float a0 = 0.f, a1 = 0.f, a2 = 0.f;
      for (int c = 0; c < 32; ++c) {
        float w = Wh2[oo * 32 + c];
        a0 = fmaf(w, pl[c][0], a0);
        a1 = fmaf(w, pl[c][1], a1);
        a2 = fmaf(w, pl[c][2], a2);
      }
      M[0][oo] = a0 + GS_EPSF * gs[bk * 9 + 0 * 3 + oo];
      M[1][oo] = a1 + GS_EPSF * gs[bk * 9 + 1 * 3 + oo];
      M[2][oo] = a2 + GS_EPSF * gs[bk * 9 + 2 * 3 + oo];
    }
    float e1[3], e2[3], e3[3], u[3];
    float nn = sqrtf(M[0][0] * M[0][0] + M[1][0] * M[1][0] + M[2][0] * M[2][0]) + EPSF;
#pragma unroll
    for (int r = 0; r < 3; ++r) e1[r] = M[r][0] / nn;
    float d12 = e1[0] * M[0][1] + e1[1] * M[1][1] + e1[2] * M[2][1];
#pragma unroll
    for (int r = 0; r < 3; ++r) u[r] = M[r][1] - d12 * e1[r];
    nn = sqrtf(u[0] * u[0] + u[1] * u[1] + u[2] * u[2]) + EPSF;
#pragma unroll
    for (int r = 0; r < 3; ++r) e2[r] = u[r] / nn;
    float d13 = e1[0] * M[0][2] + e1[1] * M[1][2] + e1[2] * M[2][2];
    float d23 = e2[0] * M[0][2] + e2[1] * M[1][2] + e2[2] * M[2][2];
#pragma unroll
    for (int r = 0; r < 3; ++r) u[r] = M[r][2] - d13 * e1[r] - d23 * e2[r];
    nn = sqrtf(u[0] * u[0] + u[1] * u[1] + u[2] * u[2]) + EPSF;
#pragma unroll
    for (int r = 0; r < 3; ++r) e3[r] = u[r] / nn;
    float det = e1[0] * (e2[1] * e3[2] - e2[2] * e3[1])
              - e1[1] * (e2[0] * e3[2] - e2[2] * e3[0])
              + e1[2] * (e2[0] * e3[1] - e2[1] * e3[0]);
#pragma unroll
    for (int r = 0; r < 3; ++r) {
      out[bk * 9 + r * 3 + 0] = e1[r] * det;
      out[bk * 9 + r * 3 + 1] = e2[r];
      out[bk * 9 + r * 3 + 2] = e3[r];
    }
  }
}

// ---------------------------------------------------------------------------
extern "C" void kernel_launch(void* const* d_in, const int* in_sizes, int n_in,
                              void* d_out, int out_size, void* d_ws, size_t ws_size,
                              hipStream_t stream) {
  (void)in_sizes; (void)n_in; (void)out_size; (void)ws_size;
  const float* node = (const float*)d_in[0];
  const float* W1f = (const float*)d_in[4];
  const float* W1d = (const float*)d_in[5];
  const float* Wp1 = (const float*)d_in[6];
  const float* Wp3 = (const float*)d_in[7];
  const float* Wh2 = (const float*)d_in[8];
  const float* z   = (const float*)d_in[9];
  const float* gs  = (const float*)d_in[10];

  float4* pts      = (float4*)d_ws;                      // 65536 f4 = 1 MB
  int4*   knn4     = (int4*)(pts + (size_t)BKT * NPT * 2);   // 512 KB
  float4* partials = (float4*)(knn4 + (size_t)BKT * NPT);    // 16*32*256 f4 = 2 MB
  float*  out      = (float*)d_out;

  prep_coords    <<<BKT * NPT / 256, 256, 0, stream>>>(node, z, pts);
  knn_kernel     <<<BKT * 32, 512, 0, stream>>>(pts, knn4);
  feature_kernel <<<BKT * 256, 128, 0, stream>>>(pts, knn4, W1f, W1d, Wp1, Wp3, partials);
  poolhead_kernel<<<BKT, 256, 0, stream>>>(partials, Wh2, gs, out);
}